// Round 5
// baseline (143.561 us; speedup 1.0000x reference)
//
#include <hip/hip_runtime.h>
#include <math.h>

#define T_DIM 2048
#define N_B   2
#define C_DIM 1024
#define H_DIM 16
#define DH    64
#define M_DIM 4096
#define WIN   128

typedef _Float16 h8 __attribute__((ext_vector_type(8)));
typedef float    f4 __attribute__((ext_vector_type(4)));

#if __has_builtin(__builtin_amdgcn_exp2f)
#define EXP2(x) __builtin_amdgcn_exp2f(x)
#else
#define EXP2(x) __expf((x) * 0.693147180559945f)
#endif

// ---------------------------------------------------------------------------
// async global->LDS, 16B per lane
// ---------------------------------------------------------------------------
__device__ __forceinline__ void glds16(const _Float16* g, _Float16* l) {
    typedef const __attribute__((address_space(1))) unsigned int guint;
    typedef __attribute__((address_space(3))) unsigned int luint;
    __builtin_amdgcn_global_load_lds((guint*)g, (luint*)l, 16, 0, 0);
}

// ---------------------------------------------------------------------------
// fp32 -> fp16 conversion prepass (7 arrays in one launch)
// ---------------------------------------------------------------------------
struct CvtA { const float* s; _Float16* d; int n; };
struct Cvt7 { CvtA a[7]; };

__global__ __launch_bounds__(256) void cvt_k(Cvt7 c) {
    CvtA A = c.a[blockIdx.y];
    const int i = (blockIdx.x * 256 + threadIdx.x) * 8;
    if (i >= A.n) return;
    const float4 v0 = *(const float4*)&A.s[i];
    const float4 v1 = *(const float4*)&A.s[i + 4];
    h8 o;
    o[0] = (_Float16)v0.x; o[1] = (_Float16)v0.y;
    o[2] = (_Float16)v0.z; o[3] = (_Float16)v0.w;
    o[4] = (_Float16)v1.x; o[5] = (_Float16)v1.y;
    o[6] = (_Float16)v1.z; o[7] = (_Float16)v1.w;
    *(h8*)&A.d[i] = o;
}

// ---------------------------------------------------------------------------
// Fused Q/K/V projection (unchanged from round 4)
// ---------------------------------------------------------------------------
struct QkvArgs {
    const _Float16* x[3];
    const _Float16* w[3];
    const float*    b[3];
    _Float16*       out[3];
};

__global__ __launch_bounds__(256) void proj_qkv(QkvArgs args) {
    const int z = blockIdx.z;
    const _Float16* __restrict__ A = args.x[z];
    const _Float16* __restrict__ B = args.w[z];
    const float* __restrict__ bias = args.b[z];
    _Float16* __restrict__ out     = args.out[z];

    __shared__ _Float16 Asm[128 * 32];
    __shared__ _Float16 Bsm[128 * 32];
    const int tid  = threadIdx.x;
    const int lane = tid & 63;
    const int wave = tid >> 6;
    const int wr = wave >> 1, wc = wave & 1;
    const int l15 = lane & 15, hi = lane >> 4;
    const int m0 = blockIdx.x << 7;
    const int o0 = blockIdx.y << 7;

    f4 acc[4][4];
    const f4 z4 = {0.f, 0.f, 0.f, 0.f};
#pragma unroll
    for (int i = 0; i < 4; ++i)
#pragma unroll
        for (int j = 0; j < 4; ++j) acc[i][j] = z4;

    for (int k0 = 0; k0 < C_DIM; k0 += 32) {
        __syncthreads();
#pragma unroll
        for (int c = 0; c < 2; ++c) {
            const int chunk = tid + c * 256;
            const int row = chunk >> 2, c8 = (chunk & 3) << 3;
            glds16(&A[(size_t)(m0 + row) * C_DIM + k0 + c8], &Asm[chunk << 3]);
            glds16(&B[(size_t)(o0 + row) * C_DIM + k0 + c8], &Bsm[chunk << 3]);
        }
        __syncthreads();

        h8 a[4], b[4];
#pragma unroll
        for (int mr = 0; mr < 4; ++mr)
            a[mr] = *(const h8*)&Asm[(wr * 64 + mr * 16 + l15) * 32 + hi * 8];
#pragma unroll
        for (int nf = 0; nf < 4; ++nf)
            b[nf] = *(const h8*)&Bsm[(wc * 64 + nf * 16 + l15) * 32 + hi * 8];
#pragma unroll
        for (int mr = 0; mr < 4; ++mr)
#pragma unroll
            for (int nf = 0; nf < 4; ++nf)
                acc[mr][nf] = __builtin_amdgcn_mfma_f32_16x16x32_f16(
                    a[mr], b[nf], acc[mr][nf], 0, 0, 0);
    }

#pragma unroll
    for (int nf = 0; nf < 4; ++nf) {
        const int o = o0 + wc * 64 + nf * 16 + l15;
        const float bb = bias[o];
        const int hh = o >> 6, d = o & 63;
#pragma unroll
        for (int mr = 0; mr < 4; ++mr)
#pragma unroll
            for (int reg = 0; reg < 4; ++reg) {
                const int m = m0 + wr * 64 + mr * 16 + 4 * hi + reg;
                const float val = acc[mr][nf][reg] + bb;
                const int t = m >> 1, n = m & 1;
                if (z == 2) {
                    out[(((size_t)(n * H_DIM + hh)) * DH + d) * T_DIM + t] = (_Float16)val;
                } else {
                    out[(((size_t)(n * H_DIM + hh)) * T_DIM + t) * DH + d] = (_Float16)val;
                }
            }
    }
}

// ---------------------------------------------------------------------------
// Output projection (unchanged from round 4)
// ---------------------------------------------------------------------------
__global__ __launch_bounds__(256) void proj_o(
    const _Float16* __restrict__ A, const _Float16* __restrict__ B,
    const float* __restrict__ bias, float* __restrict__ out)
{
    __shared__ _Float16 Asm[128 * 32];
    __shared__ _Float16 Bsm[128 * 32];
    const int tid  = threadIdx.x;
    const int lane = tid & 63;
    const int wave = tid >> 6;
    const int wr = wave >> 1, wc = wave & 1;
    const int l15 = lane & 15, hi = lane >> 4;
    const int m0 = blockIdx.x << 7;
    const int o0 = blockIdx.y << 7;

    f4 acc[4][4];
    const f4 z4 = {0.f, 0.f, 0.f, 0.f};
#pragma unroll
    for (int i = 0; i < 4; ++i)
#pragma unroll
        for (int j = 0; j < 4; ++j) acc[i][j] = z4;

    for (int k0 = 0; k0 < C_DIM; k0 += 32) {
        __syncthreads();
#pragma unroll
        for (int c = 0; c < 2; ++c) {
            const int chunk = tid + c * 256;
            const int row = chunk >> 2, c8 = (chunk & 3) << 3;
            glds16(&A[(size_t)(m0 + row) * C_DIM + k0 + c8], &Asm[chunk << 3]);
            glds16(&B[(size_t)(o0 + row) * C_DIM + k0 + c8], &Bsm[chunk << 3]);
        }
        __syncthreads();

        h8 a[4], b[4];
#pragma unroll
        for (int mr = 0; mr < 4; ++mr)
            a[mr] = *(const h8*)&Asm[(wr * 64 + mr * 16 + l15) * 32 + hi * 8];
#pragma unroll
        for (int nf = 0; nf < 4; ++nf)
            b[nf] = *(const h8*)&Bsm[(wc * 64 + nf * 16 + l15) * 32 + hi * 8];
#pragma unroll
        for (int mr = 0; mr < 4; ++mr)
#pragma unroll
            for (int nf = 0; nf < 4; ++nf)
                acc[mr][nf] = __builtin_amdgcn_mfma_f32_16x16x32_f16(
                    a[mr], b[nf], acc[mr][nf], 0, 0, 0);
    }

#pragma unroll
    for (int nf = 0; nf < 4; ++nf) {
        const int o = o0 + wc * 64 + nf * 16 + l15;
        const float bb = bias[o];
#pragma unroll
        for (int mr = 0; mr < 4; ++mr)
#pragma unroll
            for (int reg = 0; reg < 4; ++reg) {
                const int m = m0 + wr * 64 + mr * 16 + 4 * hi + reg;
                out[(size_t)m * C_DIM + o] = acc[mr][nf][reg] + bb;
            }
    }
}

// ---------------------------------------------------------------------------
// Flash attention v5: 2-wave blocks; both waves own the SAME 32 q-rows and
// split the kept K-tiles round-robin (in-block flash split-K). Defer-max
// softmax (+3 headroom) with per-lane partial l (single end reduce). Waves
// merge (m, l, O) through LDS at the end; wave 0 writes Y.
// ---------------------------------------------------------------------------
__global__ __launch_bounds__(128, 3) void attn_v5(
    const _Float16* __restrict__ QH, const _Float16* __restrict__ KH,
    const _Float16* __restrict__ VT, const int* __restrict__ key_length,
    _Float16* __restrict__ Y)
{
    __shared__ _Float16 Ps[2][32][72];   // per-wave P routing tile
    __shared__ float OfL[64][33];        // wave1 O exchange (padded: no bank conflict)
    __shared__ float mlL[32][2];         // wave1 per-row {m, l}

    const int nh = blockIdx.x;
    const int n  = nh >> 4;
    const int h  = nh & 15;
    const int qw = blockIdx.y << 5;      // 32 query rows per block
    const int kl = key_length[n];
    const int tid  = threadIdx.x;
    const int wave = tid >> 6;
    const int lane = tid & 63;
    const int l15 = lane & 15, hi = lane >> 4;

    const size_t hb = (size_t)nh * T_DIM * DH;
    const _Float16* Qb = QH + hb;
    const _Float16* Kb = KH + hb;
    const _Float16* Vb = VT + hb;        // [d][t] within this head

    // Q A-fragments (both waves load the same rows)
    h8 qa[2][2];
#pragma unroll
    for (int mr = 0; mr < 2; ++mr)
#pragma unroll
        for (int ks = 0; ks < 2; ++ks)
            qa[mr][ks] = *(const h8*)&Qb[(size_t)(qw + mr * 16 + l15) * DH + ks * 32 + hi * 8];

    f4 O[2][4];
    const f4 z4 = {0.f, 0.f, 0.f, 0.f};
#pragma unroll
    for (int mr = 0; mr < 2; ++mr)
#pragma unroll
        for (int df = 0; df < 4; ++df) O[mr][df] = z4;
    float m_i[2][4], lp[2][4];
#pragma unroll
    for (int mr = 0; mr < 2; ++mr)
#pragma unroll
        for (int r = 0; r < 4; ++r) { m_i[mr][r] = -1e30f; lp[mr][r] = 0.f; }

    const float SC = 0.18033688f;        // (1/sqrt(64)) * log2(e)

    int cnt = 0;
    for (int k0 = 0; k0 < T_DIM; k0 += 64) {
        const bool keep = (k0 < kl) || (k0 <= qw + 31 + WIN && k0 + 63 >= qw - WIN);
        if (!keep) continue;
        const bool mine = ((cnt & 1) == wave);
        ++cnt;
        if (!mine) continue;
        // fully unmasked? prefix covers tile, or band covers all 32x64 pairs
        const bool full = (k0 + 63 < kl) ||
                          (k0 >= qw + 31 - WIN && k0 + 63 <= qw + WIN);

        // K fragments straight from L2
        h8 kb[2][4];
#pragma unroll
        for (int ks = 0; ks < 2; ++ks)
#pragma unroll
            for (int cf = 0; cf < 4; ++cf)
                kb[ks][cf] = *(const h8*)&Kb[(size_t)(k0 + cf * 16 + l15) * DH + ks * 32 + hi * 8];

        // S = Q K^T
        f4 sacc[2][4];
#pragma unroll
        for (int mr = 0; mr < 2; ++mr)
#pragma unroll
            for (int cf = 0; cf < 4; ++cf) sacc[mr][cf] = z4;
#pragma unroll
        for (int ks = 0; ks < 2; ++ks)
#pragma unroll
            for (int mr = 0; mr < 2; ++mr)
#pragma unroll
                for (int cf = 0; cf < 4; ++cf)
                    sacc[mr][cf] = __builtin_amdgcn_mfma_f32_16x16x32_f16(
                        qa[mr][ks], kb[ks][cf], sacc[mr][cf], 0, 0, 0);

        // V fragments issued now; latency hides under softmax
        h8 vb[2][4];
#pragma unroll
        for (int ks = 0; ks < 2; ++ks)
#pragma unroll
            for (int df = 0; df < 4; ++df)
                vb[ks][df] = *(const h8*)&Vb[(size_t)(df * 16 + l15) * T_DIM + k0 + ks * 32 + hi * 8];

        // scale + mask in place
#pragma unroll
        for (int mr = 0; mr < 2; ++mr) {
            if (full) {
#pragma unroll
                for (int cf = 0; cf < 4; ++cf)
#pragma unroll
                    for (int reg = 0; reg < 4; ++reg)
                        sacc[mr][cf][reg] *= SC;
            } else {
#pragma unroll
                for (int cf = 0; cf < 4; ++cf)
#pragma unroll
                    for (int reg = 0; reg < 4; ++reg) {
                        const int i = qw + mr * 16 + 4 * hi + reg;
                        const int j = k0 + cf * 16 + l15;
                        const int dd = i - j;
                        const bool ok = (dd <= WIN && dd >= -WIN) || (j < kl);
                        sacc[mr][cf][reg] = ok ? sacc[mr][cf][reg] * SC : -1e9f;
                    }
            }
        }

        // defer-max check: per-lane local max vs running max
        float lm[2][4];
        bool need = false;
#pragma unroll
        for (int mr = 0; mr < 2; ++mr)
#pragma unroll
            for (int reg = 0; reg < 4; ++reg) {
                lm[mr][reg] = fmaxf(fmaxf(sacc[mr][0][reg], sacc[mr][1][reg]),
                                    fmaxf(sacc[mr][2][reg], sacc[mr][3][reg]));
                need = need || (lm[mr][reg] > m_i[mr][reg]);
            }
        if (__any(need)) {
#pragma unroll
            for (int mr = 0; mr < 2; ++mr)
#pragma unroll
                for (int reg = 0; reg < 4; ++reg) {
                    float mt = lm[mr][reg];
                    mt = fmaxf(mt, __shfl_xor(mt, 1));
                    mt = fmaxf(mt, __shfl_xor(mt, 2));
                    mt = fmaxf(mt, __shfl_xor(mt, 4));
                    mt = fmaxf(mt, __shfl_xor(mt, 8));
                    const float mnew = fmaxf(m_i[mr][reg], mt + 3.0f);  // headroom
                    const float rr = EXP2(m_i[mr][reg] - mnew);
                    m_i[mr][reg] = mnew;
                    lp[mr][reg] *= rr;
#pragma unroll
                    for (int df = 0; df < 4; ++df) O[mr][df][reg] *= rr;
                }
        }

        // p = exp2(s - m); accumulate per-lane l; store P for PV routing
#pragma unroll
        for (int mr = 0; mr < 2; ++mr)
#pragma unroll
            for (int reg = 0; reg < 4; ++reg) {
                const int row = mr * 16 + 4 * hi + reg;
                const float mi = m_i[mr][reg];
                float acc = 0.f;
#pragma unroll
                for (int cf = 0; cf < 4; ++cf) {
                    const float p = EXP2(sacc[mr][cf][reg] - mi);
                    acc += p;
                    Ps[wave][row][cf * 16 + l15] = (_Float16)p;
                }
                lp[mr][reg] += acc;
            }

        // O += P V
        h8 pa[2][2];
#pragma unroll
        for (int mr = 0; mr < 2; ++mr)
#pragma unroll
            for (int ks = 0; ks < 2; ++ks)
                pa[mr][ks] = *(const h8*)&Ps[wave][mr * 16 + l15][ks * 32 + hi * 8];
#pragma unroll
        for (int ks = 0; ks < 2; ++ks)
#pragma unroll
            for (int mr = 0; mr < 2; ++mr)
#pragma unroll
                for (int df = 0; df < 4; ++df)
                    O[mr][df] = __builtin_amdgcn_mfma_f32_16x16x32_f16(
                        pa[mr][ks], vb[ks][df], O[mr][df], 0, 0, 0);
    }

    // reduce per-lane l across the 16 l15 lanes (once)
    float lf[2][4];
#pragma unroll
    for (int mr = 0; mr < 2; ++mr)
#pragma unroll
        for (int reg = 0; reg < 4; ++reg) {
            float l = lp[mr][reg];
            l += __shfl_xor(l, 1); l += __shfl_xor(l, 2);
            l += __shfl_xor(l, 4); l += __shfl_xor(l, 8);
            lf[mr][reg] = l;
        }

    // wave 1 exports its state
    if (wave == 1) {
#pragma unroll
        for (int mr = 0; mr < 2; ++mr)
#pragma unroll
            for (int df = 0; df < 4; ++df)
#pragma unroll
                for (int reg = 0; reg < 4; ++reg)
                    OfL[lane][mr * 16 + df * 4 + reg] = O[mr][df][reg];
        if (l15 == 0) {
#pragma unroll
            for (int mr = 0; mr < 2; ++mr)
#pragma unroll
                for (int reg = 0; reg < 4; ++reg) {
                    const int row = mr * 16 + 4 * hi + reg;
                    mlL[row][0] = m_i[mr][reg];
                    mlL[row][1] = lf[mr][reg];
                }
        }
    }
    __syncthreads();
    if (wave == 1) return;

    // wave 0 merges and writes Y (fp16, row i*2+n, col h*64+d)
#pragma unroll
    for (int mr = 0; mr < 2; ++mr)
#pragma unroll
        for (int reg = 0; reg < 4; ++reg) {
            const int row = mr * 16 + 4 * hi + reg;
            const float m0v = m_i[mr][reg];
            const float m1v = mlL[row][0];
            const float l1v = mlL[row][1];
            const float mm = fmaxf(m0v, m1v);
            const float a0 = EXP2(m0v - mm);
            const float a1 = EXP2(m1v - mm);
            const float den = lf[mr][reg] * a0 + l1v * a1;
            const float inv = 1.f / den;
            const int i = qw + row - mr * 16 + mr * 16;  // = qw + row
#pragma unroll
            for (int df = 0; df < 4; ++df) {
                const float o = O[mr][df][reg] * a0 +
                                OfL[lane][mr * 16 + df * 4 + reg] * a1;
                Y[((size_t)(qw + row) * N_B + n) * C_DIM + h * DH + df * 16 + l15] =
                    (_Float16)(o * inv);
            }
            (void)i;
        }
}

extern "C" void kernel_launch(void* const* d_in, const int* in_sizes, int n_in,
                              void* d_out, int out_size, void* d_ws, size_t ws_size,
                              hipStream_t stream) {
    const float* q  = (const float*)d_in[0];
    const float* k  = (const float*)d_in[1];
    const float* v  = (const float*)d_in[2];
    const float* Wq = (const float*)d_in[3];
    const float* bq = (const float*)d_in[4];
    const float* Wk = (const float*)d_in[5];
    const float* bk = (const float*)d_in[6];
    const float* Wv = (const float*)d_in[7];
    const float* bv = (const float*)d_in[8];
    const float* Wo = (const float*)d_in[9];
    const float* bo = (const float*)d_in[10];
    const int*   kl = (const int*)d_in[11];

    const int NX = M_DIM * C_DIM;   // 4194304
    const int NW = C_DIM * C_DIM;   // 1048576

    _Float16* xq = (_Float16*)d_ws;
    _Float16* xk = xq + NX;
    _Float16* xv = xk + NX;
    _Float16* wq = xv + NX;
    _Float16* wk = wq + NW;
    _Float16* wv = wk + NW;
    _Float16* wo = wv + NW;
    _Float16* QHh = wo + NW;
    _Float16* KHh = QHh + NX;
    _Float16* VTh = KHh + NX;
    _Float16* Yh  = xq;             // reuse xq after projections

    Cvt7 c;
    c.a[0] = {q,  xq, NX}; c.a[1] = {k,  xk, NX}; c.a[2] = {v,  xv, NX};
    c.a[3] = {Wq, wq, NW}; c.a[4] = {Wk, wk, NW};
    c.a[5] = {Wv, wv, NW}; c.a[6] = {Wo, wo, NW};
    cvt_k<<<dim3(NX / (256 * 8), 7), 256, 0, stream>>>(c);

    QkvArgs qa;
    qa.x[0] = xq; qa.x[1] = xk; qa.x[2] = xv;
    qa.w[0] = wq; qa.w[1] = wk; qa.w[2] = wv;
    qa.b[0] = bq; qa.b[1] = bk; qa.b[2] = bv;
    qa.out[0] = QHh; qa.out[1] = KHh; qa.out[2] = VTh;
    proj_qkv<<<dim3(M_DIM / 128, C_DIM / 128, 3), 256, 0, stream>>>(qa);

    attn_v5<<<dim3(N_B * H_DIM, T_DIM / 32), 128, 0, stream>>>(QHh, KHh, VTh, kl, Yh);

    proj_o<<<dim3(M_DIM / 128, C_DIM / 128), 256, 0, stream>>>(Yh, wo, bo, (float*)d_out);
}